// Round 1
// baseline (1802.192 us; speedup 1.0000x reference)
//
#include <hip/hip_runtime.h>
#include <math.h>

#define BB 128
#define HH 512
#define WW 512
#define PP 64
#define DD 4
#define EPSF 1e-5f

// ---------------- Kernel 1: per-batch scaled mean/std of x ----------------
__global__ __launch_bounds__(256) void stats_kernel(const float* __restrict__ x,
                                                    float* __restrict__ stats) {
    int b = blockIdx.x;
    const float* X = x + (size_t)b * (HH * WW);
    double s = 0.0, sq = 0.0;
    for (int i = threadIdx.x; i < HH * WW; i += 256) {
        float v = X[i];
        s += v;
        sq += (double)v * v;
    }
    __shared__ double rs[256], rq[256];
    rs[threadIdx.x] = s; rq[threadIdx.x] = sq;
    __syncthreads();
    for (int st = 128; st > 0; st >>= 1) {
        if (threadIdx.x < st) {
            rs[threadIdx.x] += rs[threadIdx.x + st];
            rq[threadIdx.x] += rq[threadIdx.x + st];
        }
        __syncthreads();
    }
    if (threadIdx.x == 0) {
        double n = (double)(HH * WW);
        double mean = rs[0] / n;
        double var = (rq[0] - n * mean * mean) / (n - 1.0);
        stats[b * 2 + 0] = (float)(mean * 64.0);      // x_mean * scale
        stats[b * 2 + 1] = (float)(sqrt(var) * 64.0); // x_std * scale
    }
}

// ---------------- Kernel 2: fused big GEMM + softmax colsums + p_t ----------------
// One block per (b, side, d).  side 0 = "j" (rows of x), side 1 = "i" (cols of x).
// Computes T = Xv @ [Wrel | Wo]  ([512,128]) tile by tile (64 rows at a time):
//   - cols 0..63  -> exp() column-sum accumulation (flat softmax colsums)
//   - cols 64..127 -> T_o; accumulate p_t += T_o^T @ Wp_tile
__global__ __launch_bounds__(256) void fused_proj_kernel(
    const float* __restrict__ x,
    const float* __restrict__ o_xj, const float* __restrict__ o_xi,
    const float* __restrict__ p_xj, const float* __restrict__ p_xi,
    const float* __restrict__ o_rel_xj, const float* __restrict__ o_rel_xi,
    float* __restrict__ relsum, float* __restrict__ pt)
{
    int blk = blockIdx.x;
    int b = blk >> 3;
    int side = (blk >> 2) & 1;
    int d = blk & 3;

    const float* Wrel = (side ? o_rel_xi : o_rel_xj) + (size_t)d * (512 * 64);
    const float* Wo   = (side ? o_xi     : o_xj)     + (size_t)d * (512 * 64);
    const float* Wp   = (side ? p_xi     : p_xj)     + (size_t)d * (512 * 64);
    const float* X = x + (size_t)b * (512 * 512);

    __shared__ float Xs[16][68];    // [k][row]
    __shared__ float Ws[16][128];   // [k][col]  cols: 0..63 rel, 64..127 o
    __shared__ float To[64][68];    // o_t tile [row][p]
    __shared__ float Wps[64][68];   // Wp tile [row][q]
    __shared__ float red[16][64];
    __shared__ float cs[64];
    __shared__ float total_s;

    int tid = threadIdx.x;
    int tx = tid & 15;   // 0..15
    int ty = tid >> 4;   // 0..15

    float paccum[4][4];
    #pragma unroll
    for (int i = 0; i < 4; i++)
        #pragma unroll
        for (int j = 0; j < 4; j++) paccum[i][j] = 0.f;
    float esum[8];
    #pragma unroll
    for (int j = 0; j < 8; j++) esum[j] = 0.f;

    for (int r0 = 0; r0 < 512; r0 += 64) {
        float acc[4][8];
        #pragma unroll
        for (int i = 0; i < 4; i++)
            #pragma unroll
            for (int j = 0; j < 8; j++) acc[i][j] = 0.f;

        for (int k0 = 0; k0 < 512; k0 += 16) {
            // stage X tile: Xs[kk][r] = Xv[r0+r][k0+kk]
            if (side == 0) {
                int kk = tid & 15, r = tid >> 4;
                #pragma unroll
                for (int it = 0; it < 4; it++, r += 16)
                    Xs[kk][r] = X[(size_t)(r0 + r) * 512 + (k0 + kk)];
            } else {
                int r = tid & 63, kk = tid >> 6;
                #pragma unroll
                for (int it = 0; it < 4; it++, kk += 4)
                    Xs[kk][r] = X[(size_t)(k0 + kk) * 512 + (r0 + r)];
            }
            // stage W tile
            {
                int c = tid & 127, kk = tid >> 7;
                const float* Wsrc = (c < 64) ? (Wrel + c) : (Wo + (c - 64));
                #pragma unroll
                for (int it = 0; it < 8; it++, kk += 2)
                    Ws[kk][c] = Wsrc[(size_t)(k0 + kk) * 64];
            }
            __syncthreads();
            #pragma unroll
            for (int kk = 0; kk < 16; kk++) {
                float4 a  = *(const float4*)&Xs[kk][ty * 4];
                float4 b0 = *(const float4*)&Ws[kk][tx * 8];
                float4 b1 = *(const float4*)&Ws[kk][tx * 8 + 4];
                float av[4] = {a.x, a.y, a.z, a.w};
                float bv[8] = {b0.x, b0.y, b0.z, b0.w, b1.x, b1.y, b1.z, b1.w};
                #pragma unroll
                for (int i = 0; i < 4; i++)
                    #pragma unroll
                    for (int j = 0; j < 8; j++)
                        acc[i][j] = fmaf(av[i], bv[j], acc[i][j]);
            }
            __syncthreads();
        }

        // consume tile: rel cols -> exp colsums; o cols -> To staging
        if (tx < 8) {
            #pragma unroll
            for (int i = 0; i < 4; i++)
                #pragma unroll
                for (int j = 0; j < 8; j++)
                    esum[j] += expf(acc[i][j]);
        } else {
            #pragma unroll
            for (int i = 0; i < 4; i++) {
                float4 v0 = make_float4(acc[i][0], acc[i][1], acc[i][2], acc[i][3]);
                float4 v1 = make_float4(acc[i][4], acc[i][5], acc[i][6], acc[i][7]);
                *(float4*)&To[ty * 4 + i][(tx - 8) * 8]     = v0;
                *(float4*)&To[ty * 4 + i][(tx - 8) * 8 + 4] = v1;
            }
        }
        // stage Wp tile rows r0..r0+63
        {
            int q = tid & 63, r = tid >> 6;
            #pragma unroll
            for (int it = 0; it < 16; it++, r += 4)
                Wps[r][q] = Wp[(size_t)(r0 + r) * 64 + q];
        }
        __syncthreads();
        // paccum[p][q] += sum_r To[r][p] * Wps[r][q]; p = ty*4+i, q = tx*4+j
        for (int r = 0; r < 64; r++) {
            float4 aa = *(const float4*)&To[r][ty * 4];
            float4 bb = *(const float4*)&Wps[r][tx * 4];
            float av[4] = {aa.x, aa.y, aa.z, aa.w};
            float bv[4] = {bb.x, bb.y, bb.z, bb.w};
            #pragma unroll
            for (int i = 0; i < 4; i++)
                #pragma unroll
                for (int j = 0; j < 4; j++)
                    paccum[i][j] = fmaf(av[i], bv[j], paccum[i][j]);
        }
        __syncthreads();
    }

    // reduce exp colsums -> normalized softmax colsums
    if (tx < 8) {
        #pragma unroll
        for (int j = 0; j < 8; j++) red[ty][tx * 8 + j] = esum[j];
    }
    __syncthreads();
    if (tid < 64) {
        float s = 0.f;
        for (int t = 0; t < 16; t++) s += red[t][tid];
        cs[tid] = s;
    }
    __syncthreads();
    if (tid == 0) {
        float tot = 0.f;
        for (int i = 0; i < 64; i++) tot += cs[i];
        total_s = tot;
    }
    __syncthreads();
    size_t base = (size_t)(b * 2 + side) * 4 + d;
    if (tid < 64) relsum[base * 64 + tid] = cs[tid] / total_s;

    float* ptout = pt + base * 4096;
    #pragma unroll
    for (int i = 0; i < 4; i++)
        #pragma unroll
        for (int j = 0; j < 4; j++)
            ptout[(size_t)(ty * 4 + i) * 64 + tx * 4 + j] = paccum[i][j];
}

// ---------------- Kernel 3: finalize per batch ----------------
__global__ __launch_bounds__(256) void finalize_kernel(
    const float* __restrict__ relsum, const float* __restrict__ pt,
    const float* __restrict__ p_rel_xj, const float* __restrict__ p_rel_xi,
    const float* __restrict__ stats, float* __restrict__ out)
{
    int b = blockIdx.x;
    int tid = threadIdx.x, tx = tid & 15, ty = tid >> 4;
    __shared__ float Ptj[64][65], Pti[64][65], Wr[64][65];
    __shared__ float red[16][64];
    __shared__ float fj[64], fi[64];
    __shared__ float rs[256], rq[256];
    __shared__ float bc[2];

    float out_acc[4][4];
    #pragma unroll
    for (int i = 0; i < 4; i++)
        #pragma unroll
        for (int j = 0; j < 4; j++) out_acc[i][j] = 0.f;

    float x_mean = stats[b * 2 + 0];
    float x_std  = stats[b * 2 + 1];

    for (int d = 0; d < DD; d++) {
        const float* ptj = pt + ((size_t)(b * 2 + 0) * 4 + d) * 4096;
        const float* pti = pt + ((size_t)(b * 2 + 1) * 4 + d) * 4096;
        for (int it = 0; it < 16; it++) {
            int idx = tid + it * 256;
            Ptj[idx >> 6][idx & 63] = ptj[idx];
            Pti[idx >> 6][idx & 63] = pti[idx];
        }
        __syncthreads();

        // ---- side j: q = Ptj @ p_rel_xj[d], softmax colsums, f_j ----
        for (int s = 0; s < 2; s++) {
            const float* prel = (s == 0) ? (p_rel_xj + (size_t)d * 4096)
                                         : (p_rel_xi + (size_t)d * 4096);
            for (int it = 0; it < 16; it++) {
                int idx = tid + it * 256;
                Wr[idx >> 6][idx & 63] = prel[idx];
            }
            __syncthreads();
            float cpart[4] = {0.f, 0.f, 0.f, 0.f};
            for (int i = 0; i < 4; i++) {
                int p = ty * 4 + i;
                float q[4] = {0.f, 0.f, 0.f, 0.f};
                for (int r = 0; r < 64; r++) {
                    float a = (s == 0) ? Ptj[p][r] : Pti[p][r];
                    #pragma unroll
                    for (int j = 0; j < 4; j++)
                        q[j] = fmaf(a, Wr[r][tx * 4 + j], q[j]);
                }
                #pragma unroll
                for (int j = 0; j < 4; j++) cpart[j] += expf(q[j]);
            }
            #pragma unroll
            for (int j = 0; j < 4; j++) red[ty][tx * 4 + j] = cpart[j];
            __syncthreads();
            float* ftgt = (s == 0) ? fj : fi;
            if (tid < 64) {
                float cssum = 0.f;
                for (int t = 0; t < 16; t++) cssum += red[t][tid];
                ftgt[tid] = cssum;
            }
            __syncthreads();
            if (tid == 0) {
                float tot = 0.f;
                for (int i = 0; i < 64; i++) tot += ftgt[i];
                bc[0] = tot;
            }
            __syncthreads();
            if (tid < 64) {
                float prel_sum = ftgt[tid] / bc[0];
                float orel = relsum[((size_t)(b * 2 + s) * 4 + d) * 64 + tid];
                ftgt[tid] = sqrtf(orel / prel_sum);
            }
            __syncthreads();
        }

        // ---- x_buf = Ptj*fj[row] + (Pti*fi[row])^T, renormalize, accumulate ----
        float v[4][4];
        float psum = 0.f, psumsq = 0.f;
        #pragma unroll
        for (int i = 0; i < 4; i++) {
            int r = ty * 4 + i;
            #pragma unroll
            for (int j = 0; j < 4; j++) {
                int c = tx * 4 + j;
                float val = Ptj[r][c] * fj[r] + Pti[c][r] * fi[c];
                v[i][j] = val;
                psum += val;
                psumsq += val * val;
            }
        }
        rs[tid] = psum; rq[tid] = psumsq;
        __syncthreads();
        for (int st = 128; st > 0; st >>= 1) {
            if (tid < st) { rs[tid] += rs[tid + st]; rq[tid] += rq[tid + st]; }
            __syncthreads();
        }
        float mean = rs[0] / 4096.f;
        float var = (rq[0] - 4096.f * mean * mean) / 4095.f;
        float inv = 1.0f / (sqrtf(var) + EPSF);
        #pragma unroll
        for (int i = 0; i < 4; i++)
            #pragma unroll
            for (int j = 0; j < 4; j++)
                out_acc[i][j] += (v[i][j] - mean) * inv * x_std + x_mean;
        __syncthreads();
    }

    #pragma unroll
    for (int i = 0; i < 4; i++)
        #pragma unroll
        for (int j = 0; j < 4; j++)
            out[(size_t)b * 4096 + (size_t)(ty * 4 + i) * 64 + tx * 4 + j] = out_acc[i][j];
}

extern "C" void kernel_launch(void* const* d_in, const int* in_sizes, int n_in,
                              void* d_out, int out_size, void* d_ws, size_t ws_size,
                              hipStream_t stream) {
    const float* x        = (const float*)d_in[0];
    const float* o_xj     = (const float*)d_in[1];
    const float* o_xi     = (const float*)d_in[2];
    const float* p_xj     = (const float*)d_in[3];
    const float* p_xi     = (const float*)d_in[4];
    const float* o_rel_xj = (const float*)d_in[5];
    const float* o_rel_xi = (const float*)d_in[6];
    const float* p_rel_xj = (const float*)d_in[7];
    const float* p_rel_xi = (const float*)d_in[8];
    float* out = (float*)d_out;

    float* stats  = (float*)d_ws;          // 256 floats
    float* relsum = stats + 256;           // 128*2*4*64 = 65536 floats
    float* pt     = relsum + 65536;        // 128*2*4*4096 = 4194304 floats (~17 MB total)

    stats_kernel<<<BB, 256, 0, stream>>>(x, stats);
    fused_proj_kernel<<<BB * 2 * DD, 256, 0, stream>>>(
        x, o_xj, o_xi, p_xj, p_xi, o_rel_xj, o_rel_xi, relsum, pt);
    finalize_kernel<<<BB, 256, 0, stream>>>(relsum, pt, p_rel_xj, p_rel_xi, stats, out);
}

// Round 2
// 433.934 us; speedup vs baseline: 4.1531x; 4.1531x over previous
//
#include <hip/hip_runtime.h>
#include <math.h>

typedef __attribute__((ext_vector_type(8))) short short8;
typedef __attribute__((ext_vector_type(4))) short short4v;
typedef __attribute__((ext_vector_type(4))) float f32x4;

#define EPSF 1e-5f

__device__ __forceinline__ short f2bf(float f) {
    union { float f; unsigned u; } v; v.f = f;
    unsigned r = (v.u + 0x7FFFu + ((v.u >> 16) & 1u)) >> 16;
    return (short)r;
}

__device__ __forceinline__ void gload16(const void* g, void* l) {
    __builtin_amdgcn_global_load_lds(
        (const __attribute__((address_space(1))) unsigned int*)g,
        (__attribute__((address_space(3))) unsigned int*)l, 16, 0, 0);
}

// ---------------- xprep: fp32 x -> bf16 x and bf16 x^T, + stats partials ----------------
__global__ __launch_bounds__(256) void xprep_kernel(const float* __restrict__ x,
                                                    short* __restrict__ xbf,
                                                    short* __restrict__ xtbf,
                                                    double* __restrict__ part) {
    int blk = blockIdx.x;               // 128 b * 64 tiles
    int b = blk >> 6, t = blk & 63;
    int tr = (t >> 3) * 64, tc = (t & 7) * 64;
    const float* X = x + (size_t)b * 262144;
    short* XB = xbf + (size_t)b * 262144;
    short* XT = xtbf + (size_t)b * 262144;
    __shared__ float tile[64][65];
    __shared__ double rs[256], rq[256];
    int tid = threadIdx.x;
    double s = 0.0, sq = 0.0;
    for (int it = 0; it < 16; it++) {
        int idx = tid + it * 256;
        int r = idx >> 6, c = idx & 63;
        float v = X[(size_t)(tr + r) * 512 + tc + c];
        tile[r][c] = v;
        XB[(size_t)(tr + r) * 512 + tc + c] = f2bf(v);
        s += v; sq += (double)v * v;
    }
    rs[tid] = s; rq[tid] = sq;
    __syncthreads();
    for (int st = 128; st > 0; st >>= 1) {
        if (tid < st) { rs[tid] += rs[tid + st]; rq[tid] += rq[tid + st]; }
        __syncthreads();
    }
    if (tid == 0) { part[blk * 2] = rs[0]; part[blk * 2 + 1] = rq[0]; }
    for (int it = 0; it < 16; it++) {
        int idx = tid + it * 256;
        int r = idx >> 6, c = idx & 63;
        XT[(size_t)(tc + r) * 512 + tr + c] = f2bf(tile[c][r]);
    }
}

// ---------------- stats ----------------
__global__ __launch_bounds__(256) void stats_p1(const float* __restrict__ x,
                                                double* __restrict__ part) {
    int blk = blockIdx.x;  // 512
    const float4* X = (const float4*)(x + (size_t)blk * 65536);
    double s = 0.0, sq = 0.0;
    for (int i = threadIdx.x; i < 16384; i += 256) {
        float4 v = X[i];
        s += (double)v.x + (double)v.y + (double)v.z + (double)v.w;
        sq += (double)v.x * v.x + (double)v.y * v.y + (double)v.z * v.z + (double)v.w * v.w;
    }
    __shared__ double rs[256], rq[256];
    rs[threadIdx.x] = s; rq[threadIdx.x] = sq;
    __syncthreads();
    for (int st = 128; st > 0; st >>= 1) {
        if (threadIdx.x < st) { rs[threadIdx.x] += rs[threadIdx.x + st]; rq[threadIdx.x] += rq[threadIdx.x + st]; }
        __syncthreads();
    }
    if (threadIdx.x == 0) { part[blk * 2] = rs[0]; part[blk * 2 + 1] = rq[0]; }
}

__global__ void stats_p2(const double* __restrict__ part, float* __restrict__ stats, int ppb) {
    int b = threadIdx.x;  // 128
    double s = 0.0, sq = 0.0;
    for (int p = 0; p < ppb; p++) { s += part[(b * ppb + p) * 2]; sq += part[(b * ppb + p) * 2 + 1]; }
    double n = 262144.0;
    double mean = s / n;
    double var = (sq - n * mean * mean) / (n - 1.0);
    stats[b * 2 + 0] = (float)(mean * 64.0);
    stats[b * 2 + 1] = (float)(sqrt(var) * 64.0);
}

// ---------------- wprep: weights -> bf16, transposed [n][k] ----------------
__global__ __launch_bounds__(256) void wprep_kernel(
    const float* __restrict__ o_xj, const float* __restrict__ o_xi,
    const float* __restrict__ p_xj, const float* __restrict__ p_xi,
    const float* __restrict__ o_rel_xj, const float* __restrict__ o_rel_xi,
    short* __restrict__ wcat, short* __restrict__ wpt) {
    int idx = blockIdx.x * 256 + threadIdx.x;
    if (idx < 524288) {
        int k = idx & 511, n = (idx >> 9) & 127, d = (idx >> 16) & 3, sde = idx >> 18;
        float v;
        if (n < 64) v = (sde ? o_rel_xi : o_rel_xj)[(size_t)d * 32768 + (size_t)k * 64 + n];
        else        v = (sde ? o_xi : o_xj)[(size_t)d * 32768 + (size_t)k * 64 + (n - 64)];
        wcat[idx] = f2bf(v);
    } else {
        int j = idx - 524288;
        int k = j & 511, q = (j >> 9) & 63, d = (j >> 15) & 3, sde = j >> 17;
        wpt[j] = f2bf((sde ? p_xi : p_xj)[(size_t)d * 32768 + (size_t)k * 64 + q]);
    }
}

// ---------------- main MFMA kernel: one block per (b, side, d) ----------------
__global__ __launch_bounds__(256, 3) void main_mfma_kernel(
    const short* __restrict__ xbf, const short* __restrict__ xtbf,
    const short* __restrict__ wcat, const short* __restrict__ wpt,
    float* __restrict__ relsum, float* __restrict__ pt) {
    int blk = blockIdx.x;
    int b = blk >> 3, side = (blk >> 2) & 1, d = blk & 3;
    const short* Xp  = (side ? xtbf : xbf) + (size_t)b * 262144;
    const short* Wc  = wcat + (size_t)(side * 4 + d) * 65536;   // [128 n][512 k]
    const short* Wpp = wpt + (size_t)(side * 4 + d) * 32768;    // [64 q][512 r]

    __shared__ __align__(16) char lds[50176];
    short* Xs  = (short*)lds;              // 8 KB: 8 subtiles of 1KB, frag-lane order
    short* Wsh = (short*)(lds + 8192);     // 8 KB
    short* Tos = (short*)(lds + 16384);    // 64 x 136 shorts (To^T, padded)
    short* Wps = (short*)(lds + 33792);    // 16 KB: 16 subtiles

    int tid = threadIdx.x;
    int w = tid >> 6, l = tid & 63, li = l & 15, lg = l >> 4;
    int wm = w >> 1, wn = w & 1;

    f32x4 zero4 = {0.f, 0.f, 0.f, 0.f};
    f32x4 ptacc[4];
    #pragma unroll
    for (int i = 0; i < 4; i++) ptacc[i] = zero4;
    float esum[4] = {0.f, 0.f, 0.f, 0.f};

    for (int mt = 0; mt < 4; mt++) {
        int r0 = mt * 128;
        f32x4 acc[4][4];
        #pragma unroll
        for (int i = 0; i < 4; i++)
            #pragma unroll
            for (int j = 0; j < 4; j++) acc[i][j] = zero4;

        for (int kt = 0; kt < 16; kt++) {
            int k0 = kt * 32;
            __syncthreads();
            #pragma unroll
            for (int ii = 0; ii < 4; ii++) {
                int s = w * 4 + ii;
                if (s < 8)
                    gload16(Xp + (size_t)(r0 + s * 16 + li) * 512 + k0 + lg * 8, Xs + s * 512);
                else
                    gload16(Wc + (size_t)((s - 8) * 16 + li) * 512 + k0 + lg * 8, Wsh + (s - 8) * 512);
            }
            __syncthreads();
            short8 af[4], bfv[4];
            #pragma unroll
            for (int i = 0; i < 4; i++) af[i] = *(const short8*)(Xs + (wm * 4 + i) * 512 + l * 8);
            #pragma unroll
            for (int j = 0; j < 4; j++) bfv[j] = *(const short8*)(Wsh + (wn * 4 + j) * 512 + l * 8);
            #pragma unroll
            for (int i = 0; i < 4; i++)
                #pragma unroll
                for (int j = 0; j < 4; j++)
                    acc[i][j] = __builtin_amdgcn_mfma_f32_16x16x32_bf16(af[i], bfv[j], acc[i][j], 0, 0, 0);
        }

        if (wn == 0) {
            // rel columns: exp colsum accumulation (cols = j*16 + li)
            #pragma unroll
            for (int i = 0; i < 4; i++)
                #pragma unroll
                for (int j = 0; j < 4; j++)
                    esum[j] += __expf(acc[i][j][0]) + __expf(acc[i][j][1]) +
                               __expf(acc[i][j][2]) + __expf(acc[i][j][3]);
        } else {
            // o columns: write To^T[p][r] (bf16) for the p_t matmul
            #pragma unroll
            for (int i = 0; i < 4; i++)
                #pragma unroll
                for (int j = 0; j < 4; j++) {
                    int p = j * 16 + li;
                    int rb = wm * 64 + i * 16 + lg * 4;
                    short4v tv;
                    tv.x = f2bf(acc[i][j][0]); tv.y = f2bf(acc[i][j][1]);
                    tv.z = f2bf(acc[i][j][2]); tv.w = f2bf(acc[i][j][3]);
                    *(short4v*)(Tos + p * 136 + rb) = tv;
                }
        }
        // stage Wp tile [q][r0..r0+127]
        #pragma unroll
        for (int ii = 0; ii < 4; ii++) {
            int s = w * 4 + ii;
            int kk = s >> 2, nq = s & 3;
            gload16(Wpp + (size_t)(nq * 16 + li) * 512 + r0 + kk * 32 + lg * 8, Wps + s * 512);
        }
        __syncthreads();
        // p_t += To^T @ Wp : wave w owns p rows w*16..w*16+15
        #pragma unroll
        for (int kk = 0; kk < 4; kk++) {
            short8 a = *(const short8*)(Tos + (w * 16 + li) * 136 + kk * 32 + lg * 8);
            #pragma unroll
            for (int nq = 0; nq < 4; nq++) {
                short8 bb = *(const short8*)(Wps + (kk * 4 + nq) * 512 + l * 8);
                ptacc[nq] = __builtin_amdgcn_mfma_f32_16x16x32_bf16(a, bb, ptacc[nq], 0, 0, 0);
            }
        }
    }

    __syncthreads();
    float* red = (float*)lds;
    if (wn == 0) {
        #pragma unroll
        for (int j = 0; j < 4; j++) red[wm * 256 + l * 4 + j] = esum[j];
    }
    __syncthreads();
    size_t base = (size_t)(b * 2 + side) * 4 + d;
    if (tid < 64) {
        float s = 0.f;
        #pragma unroll
        for (int w2 = 0; w2 < 2; w2++)
            #pragma unroll
            for (int g = 0; g < 4; g++)
                s += red[w2 * 256 + (g * 16 + (tid & 15)) * 4 + (tid >> 4)];
        float tot = s;
        #pragma unroll
        for (int off = 1; off < 64; off <<= 1) tot += __shfl_xor(tot, off, 64);
        relsum[base * 64 + tid] = s / tot;
    }
    float* ptout = pt + base * 4096;
    #pragma unroll
    for (int nq = 0; nq < 4; nq++)
        #pragma unroll
        for (int r = 0; r < 4; r++)
            ptout[(size_t)(w * 16 + lg * 4 + r) * 64 + nq * 16 + li] = ptacc[nq][r];
}

// ---------------- fallback fp32 fused kernel (round-1, proven) ----------------
__global__ __launch_bounds__(256) void fused_proj_kernel(
    const float* __restrict__ x,
    const float* __restrict__ o_xj, const float* __restrict__ o_xi,
    const float* __restrict__ p_xj, const float* __restrict__ p_xi,
    const float* __restrict__ o_rel_xj, const float* __restrict__ o_rel_xi,
    float* __restrict__ relsum, float* __restrict__ pt)
{
    int blk = blockIdx.x;
    int b = blk >> 3;
    int side = (blk >> 2) & 1;
    int d = blk & 3;

    const float* Wrel = (side ? o_rel_xi : o_rel_xj) + (size_t)d * (512 * 64);
    const float* Wo   = (side ? o_xi     : o_xj)     + (size_t)d * (512 * 64);
    const float* Wp   = (side ? p_xi     : p_xj)     + (size_t)d * (512 * 64);
    const float* X = x + (size_t)b * (512 * 512);

    __shared__ float Xs[16][68];
    __shared__ float Ws[16][128];
    __shared__ float To[64][68];
    __shared__ float Wps[64][68];
    __shared__ float red[16][64];
    __shared__ float cs[64];
    __shared__ float total_s;

    int tid = threadIdx.x;
    int tx = tid & 15;
    int ty = tid >> 4;

    float paccum[4][4];
    #pragma unroll
    for (int i = 0; i < 4; i++)
        #pragma unroll
        for (int j = 0; j < 4; j++) paccum[i][j] = 0.f;
    float esum[8];
    #pragma unroll
    for (int j = 0; j < 8; j++) esum[j] = 0.f;

    for (int r0 = 0; r0 < 512; r0 += 64) {
        float acc[4][8];
        #pragma unroll
        for (int i = 0; i < 4; i++)
            #pragma unroll
            for (int j = 0; j < 8; j++) acc[i][j] = 0.f;

        for (int k0 = 0; k0 < 512; k0 += 16) {
            if (side == 0) {
                int kk = tid & 15, r = tid >> 4;
                #pragma unroll
                for (int it = 0; it < 4; it++, r += 16)
                    Xs[kk][r] = X[(size_t)(r0 + r) * 512 + (k0 + kk)];
            } else {
                int r = tid & 63, kk = tid >> 6;
                #pragma unroll
                for (int it = 0; it < 4; it++, kk += 4)
                    Xs[kk][r] = X[(size_t)(k0 + kk) * 512 + (r0 + r)];
            }
            {
                int c = tid & 127, kk = tid >> 7;
                const float* Wsrc = (c < 64) ? (Wrel + c) : (Wo + (c - 64));
                #pragma unroll
                for (int it = 0; it < 8; it++, kk += 2)
                    Ws[kk][c] = Wsrc[(size_t)(k0 + kk) * 64];
            }
            __syncthreads();
            #pragma unroll
            for (int kk = 0; kk < 16; kk++) {
                float4 a  = *(const float4*)&Xs[kk][ty * 4];
                float4 b0 = *(const float4*)&Ws[kk][tx * 8];
                float4 b1 = *(const float4*)&Ws[kk][tx * 8 + 4];
                float av[4] = {a.x, a.y, a.z, a.w};
                float bv[8] = {b0.x, b0.y, b0.z, b0.w, b1.x, b1.y, b1.z, b1.w};
                #pragma unroll
                for (int i = 0; i < 4; i++)
                    #pragma unroll
                    for (int j = 0; j < 8; j++)
                        acc[i][j] = fmaf(av[i], bv[j], acc[i][j]);
            }
            __syncthreads();
        }

        if (tx < 8) {
            #pragma unroll
            for (int i = 0; i < 4; i++)
                #pragma unroll
                for (int j = 0; j < 8; j++)
                    esum[j] += expf(acc[i][j]);
        } else {
            #pragma unroll
            for (int i = 0; i < 4; i++) {
                float4 v0 = make_float4(acc[i][0], acc[i][1], acc[i][2], acc[i][3]);
                float4 v1 = make_float4(acc[i][4], acc[i][5], acc[i][6], acc[i][7]);
                *(float4*)&To[ty * 4 + i][(tx - 8) * 8]     = v0;
                *(float4*)&To[ty * 4 + i][(tx - 8) * 8 + 4] = v1;
            }
        }
        {
            int q = tid & 63, r = tid >> 6;
            #pragma unroll
            for (int it = 0; it < 16; it++, r += 4)
                Wps[r][q] = Wp[(size_t)(r0 + r) * 64 + q];
        }
        __syncthreads();
        for (int r = 0; r < 64; r++) {
            float4 aa = *(const float4*)&To[r][ty * 4];
            float4 bb = *(const float4*)&Wps[r][tx * 4];
            float av[4] = {aa.x, aa.y, aa.z, aa.w};
            float bv[4] = {bb.x, bb.y, bb.z, bb.w};
            #pragma unroll
            for (int i = 0; i < 4; i++)
                #pragma unroll
                for (int j = 0; j < 4; j++)
                    paccum[i][j] = fmaf(av[i], bv[j], paccum[i][j]);
        }
        __syncthreads();
    }

    if (tx < 8) {
        #pragma unroll
        for (int j = 0; j < 8; j++) red[ty][tx * 8 + j] = esum[j];
    }
    __syncthreads();
    if (tid < 64) {
        float s = 0.f;
        for (int t = 0; t < 16; t++) s += red[t][tid];
        cs[tid] = s;
    }
    __syncthreads();
    if (tid == 0) {
        float tot = 0.f;
        for (int i = 0; i < 64; i++) tot += cs[i];
        total_s = tot;
    }
    __syncthreads();
    size_t base = (size_t)(b * 2 + side) * 4 + d;
    if (tid < 64) relsum[base * 64 + tid] = cs[tid] / total_s;

    float* ptout = pt + base * 4096;
    #pragma unroll
    for (int i = 0; i < 4; i++)
        #pragma unroll
        for (int j = 0; j < 4; j++)
            ptout[(size_t)(ty * 4 + i) * 64 + tx * 4 + j] = paccum[i][j];
}

// ---------------- finalize per (b,d), writes contribution into ptj slot ----------------
__global__ __launch_bounds__(256) void finalize2_kernel(
    const float* __restrict__ relsum, float* __restrict__ pt,
    const float* __restrict__ p_rel_xj, const float* __restrict__ p_rel_xi,
    const float* __restrict__ stats)
{
    int blk = blockIdx.x;
    int b = blk >> 2, d = blk & 3;
    int tid = threadIdx.x, tx = tid & 15, ty = tid >> 4;
    __shared__ float Ptj[64][65], Pti[64][65], Wr[64][65];
    __shared__ float red[16][64];
    __shared__ float fj[64], fi[64];
    __shared__ float rs[256], rq[256];
    __shared__ float bc[1];

    float x_mean = stats[b * 2 + 0];
    float x_std  = stats[b * 2 + 1];

    float* ptj = pt + ((size_t)(b * 2 + 0) * 4 + d) * 4096;
    const float* pti = pt + ((size_t)(b * 2 + 1) * 4 + d) * 4096;
    for (int it = 0; it < 16; it++) {
        int idx = tid + it * 256;
        Ptj[idx >> 6][idx & 63] = ptj[idx];
        Pti[idx >> 6][idx & 63] = pti[idx];
    }
    __syncthreads();

    for (int s = 0; s < 2; s++) {
        const float* prel = (s == 0) ? (p_rel_xj + (size_t)d * 4096)
                                     : (p_rel_xi + (size_t)d * 4096);
        for (int it = 0; it < 16; it++) {
            int idx = tid + it * 256;
            Wr[idx >> 6][idx & 63] = prel[idx];
        }
        __syncthreads();
        float cpart[4] = {0.f, 0.f, 0.f, 0.f};
        for (int i = 0; i < 4; i++) {
            int p = ty * 4 + i;
            float q[4] = {0.f, 0.f, 0.f, 0.f};
            for (int r = 0; r < 64; r++) {
                float a = (s == 0) ? Ptj[p][r] : Pti[p][r];
                #pragma unroll
                for (int j = 0; j < 4; j++)
                    q[j] = fmaf(a, Wr[r][tx * 4 + j], q[j]);
            }
            #pragma unroll
            for (int j = 0; j < 4; j++) cpart[j] += __expf(q[j]);
        }
        #pragma unroll
        for (int j = 0; j < 4; j++) red[ty][tx * 4 + j] = cpart[j];
        __syncthreads();
        float* ftgt = (s == 0) ? fj : fi;
        if (tid < 64) {
            float cssum = 0.f;
            for (int t = 0; t < 16; t++) cssum += red[t][tid];
            ftgt[tid] = cssum;
        }
        __syncthreads();
        if (tid == 0) {
            float tot = 0.f;
            for (int i = 0; i < 64; i++) tot += ftgt[i];
            bc[0] = tot;
        }
        __syncthreads();
        if (tid < 64) {
            float prel_sum = ftgt[tid] / bc[0];
            float orel = relsum[((size_t)(b * 2 + s) * 4 + d) * 64 + tid];
            ftgt[tid] = sqrtf(orel / prel_sum);
        }
        __syncthreads();
    }

    float v[4][4];
    float psum = 0.f, psq = 0.f;
    #pragma unroll
    for (int i = 0; i < 4; i++) {
        int r = ty * 4 + i;
        #pragma unroll
        for (int j = 0; j < 4; j++) {
            int c = tx * 4 + j;
            float val = Ptj[r][c] * fj[r] + Pti[c][r] * fi[c];
            v[i][j] = val; psum += val; psq += val * val;
        }
    }
    rs[tid] = psum; rq[tid] = psq;
    __syncthreads();
    for (int st = 128; st > 0; st >>= 1) {
        if (tid < st) { rs[tid] += rs[tid + st]; rq[tid] += rq[tid + st]; }
        __syncthreads();
    }
    float mean = rs[0] / 4096.f;
    float var = (rq[0] - 4096.f * mean * mean) / 4095.f;
    float inv = 1.0f / (sqrtf(var) + EPSF);
    #pragma unroll
    for (int i = 0; i < 4; i++)
        #pragma unroll
        for (int j = 0; j < 4; j++)
            ptj[(size_t)(ty * 4 + i) * 64 + tx * 4 + j] = (v[i][j] - mean) * inv * x_std + x_mean;
}

// ---------------- sum over depth ----------------
__global__ __launch_bounds__(256) void sum_kernel(const float* __restrict__ pt,
                                                  float* __restrict__ out) {
    int b = blockIdx.x, tid = threadIdx.x;
    for (int it = 0; it < 16; it++) {
        int idx = tid + it * 256;
        float s = 0.f;
        #pragma unroll
        for (int d = 0; d < 4; d++)
            s += pt[((size_t)(b * 2) * 4 + d) * 4096 + idx];
        out[(size_t)b * 4096 + idx] = s;
    }
}

extern "C" void kernel_launch(void* const* d_in, const int* in_sizes, int n_in,
                              void* d_out, int out_size, void* d_ws, size_t ws_size,
                              hipStream_t stream) {
    const float* x        = (const float*)d_in[0];
    const float* o_xj     = (const float*)d_in[1];
    const float* o_xi     = (const float*)d_in[2];
    const float* p_xj     = (const float*)d_in[3];
    const float* p_xi     = (const float*)d_in[4];
    const float* o_rel_xj = (const float*)d_in[5];
    const float* o_rel_xi = (const float*)d_in[6];
    const float* p_rel_xj = (const float*)d_in[7];
    const float* p_rel_xi = (const float*)d_in[8];
    float* out = (float*)d_out;

    char* ws = (char*)d_ws;
    // layout (bytes):
    float*  stats  = (float*)(ws + 0);           // 1024
    float*  relsum = (float*)(ws + 1024);        // 262144
    float*  pt     = (float*)(ws + 263168);      // 16777216  -> end 17040384 (fallback max)
    double* spartF = (double*)(ws + 17040384);   // 131072 (fast path: 8192 partials)
    short*  xbf    = (short*)(ws + 17171456);    // 67108864
    short*  xtbf   = (short*)(ws + 84280320);    // 67108864
    short*  wcat   = (short*)(ws + 151389184);   // 1048576
    short*  wptb   = (short*)(ws + 152437760);   // 524288 -> end 152962048
    double* spartS = (double*)(ws + 263168);     // fallback alias inside pt region (dead before pt written)

    const size_t FAST_NEED = 152962048;
    if (ws_size >= FAST_NEED) {
        xprep_kernel<<<8192, 256, 0, stream>>>(x, xbf, xtbf, spartF);
        wprep_kernel<<<3072, 256, 0, stream>>>(o_xj, o_xi, p_xj, p_xi, o_rel_xj, o_rel_xi, wcat, wptb);
        stats_p2<<<1, 128, 0, stream>>>(spartF, stats, 64);
        main_mfma_kernel<<<1024, 256, 0, stream>>>(xbf, xtbf, wcat, wptb, relsum, pt);
    } else {
        stats_p1<<<512, 256, 0, stream>>>(x, spartS);
        stats_p2<<<1, 128, 0, stream>>>(spartS, stats, 4);
        fused_proj_kernel<<<1024, 256, 0, stream>>>(x, o_xj, o_xi, p_xj, p_xi,
                                                    o_rel_xj, o_rel_xi, relsum, pt);
    }
    finalize2_kernel<<<512, 256, 0, stream>>>(relsum, pt, p_rel_xj, p_rel_xi, stats);
    sum_kernel<<<128, 256, 0, stream>>>(pt, out);
}

// Round 3
// 367.919 us; speedup vs baseline: 4.8983x; 1.1794x over previous
//
#include <hip/hip_runtime.h>
#include <math.h>

typedef __attribute__((ext_vector_type(8))) short short8;
typedef __attribute__((ext_vector_type(4))) short short4v;
typedef __attribute__((ext_vector_type(4))) float f32x4;

#define EPSF 1e-5f

__device__ __forceinline__ short f2bf(float f) {
    union { float f; unsigned u; } v; v.f = f;
    unsigned r = (v.u + 0x7FFFu + ((v.u >> 16) & 1u)) >> 16;
    return (short)r;
}

__device__ __forceinline__ void gload16(const void* g, void* l) {
    __builtin_amdgcn_global_load_lds(
        (const __attribute__((address_space(1))) unsigned int*)g,
        (__attribute__((address_space(3))) unsigned int*)l, 16, 0, 0);
}

// ---------------- xprep: fp32 x -> swizzled bf16 x and x^T chunks, + stats partials ----
// Chunk layout (1 KB each): chunk C = (b*32 + R)*16 + kt; element (l*8+e) holds
//   X[R*16 + (l&15)][kt*32 + (l>>4)*8 + e]   (xtbf: same formula on X^T)
__global__ __launch_bounds__(256) void xprep_kernel(const float* __restrict__ x,
                                                    short* __restrict__ xbf,
                                                    short* __restrict__ xtbf,
                                                    double* __restrict__ part) {
    int blk = blockIdx.x;               // 128 b * 64 tiles
    int b = blk >> 6, t = blk & 63;
    int tr = (t >> 3) * 64, tc = (t & 7) * 64;
    const float* X = x + (size_t)b * 262144;
    __shared__ short tileR[64][80];     // bf16 tile, row stride 160 B (16B-aligned)
    __shared__ double rs[256], rq[256];
    int tid = threadIdx.x;

    // phase 1: coalesced read, convert, stage row-major
    {
        int r = tid >> 2, cseg = (tid & 3) * 16;
        const float* src = X + (size_t)(tr + r) * 512 + tc + cseg;
        double s = 0.0, sq = 0.0;
        short vals[16];
        #pragma unroll
        for (int q = 0; q < 4; q++) {
            float4 f = *(const float4*)(src + q * 4);
            vals[q * 4 + 0] = f2bf(f.x); vals[q * 4 + 1] = f2bf(f.y);
            vals[q * 4 + 2] = f2bf(f.z); vals[q * 4 + 3] = f2bf(f.w);
            s += (double)f.x + (double)f.y + (double)f.z + (double)f.w;
            sq += (double)f.x * f.x + (double)f.y * f.y + (double)f.z * f.z + (double)f.w * f.w;
        }
        *(short8*)&tileR[r][cseg]     = *(short8*)&vals[0];
        *(short8*)&tileR[r][cseg + 8] = *(short8*)&vals[8];
        rs[tid] = s; rq[tid] = sq;
    }
    __syncthreads();
    for (int st = 128; st > 0; st >>= 1) {
        if (tid < st) { rs[tid] += rs[tid + st]; rq[tid] += rq[tid + st]; }
        __syncthreads();
    }
    if (tid == 0) { part[blk * 2] = rs[0]; part[blk * 2 + 1] = rq[0]; }

    // phase 2: emit swizzled chunks (1 KB per wave, fully coalesced stores)
    int w = tid >> 6, l = tid & 63, li = l & 15, lg = l >> 4;
    #pragma unroll
    for (int q = 0; q < 2; q++) {
        int cc = w * 2 + q;
        int Rl = cc >> 1, ktl = cc & 1;
        short8 v = *(const short8*)&tileR[Rl * 16 + li][ktl * 32 + lg * 8];
        size_t chunk = (size_t)(b * 32 + (tr >> 4) + Rl) * 16 + (tc >> 5) + ktl;
        *(short8*)(xbf + chunk * 512 + l * 8) = v;
    }
    #pragma unroll
    for (int q = 0; q < 2; q++) {
        int cc = w * 2 + q;
        int Rl = cc >> 1, ktl = cc & 1;
        int c_loc = Rl * 16 + li;
        int rbase = ktl * 32 + lg * 8;
        short8 v;
        #pragma unroll
        for (int e = 0; e < 8; e++) v[e] = tileR[rbase + e][c_loc];
        size_t chunk = (size_t)(b * 32 + (tc >> 4) + Rl) * 16 + (tr >> 5) + ktl;
        *(short8*)(xtbf + chunk * 512 + l * 8) = v;
    }
}

// ---------------- stats (fallback p1; p2 used by both paths) ----------------
__global__ __launch_bounds__(256) void stats_p1(const float* __restrict__ x,
                                                double* __restrict__ part) {
    int blk = blockIdx.x;  // 512
    const float4* X = (const float4*)(x + (size_t)blk * 65536);
    double s = 0.0, sq = 0.0;
    for (int i = threadIdx.x; i < 16384; i += 256) {
        float4 v = X[i];
        s += (double)v.x + (double)v.y + (double)v.z + (double)v.w;
        sq += (double)v.x * v.x + (double)v.y * v.y + (double)v.z * v.z + (double)v.w * v.w;
    }
    __shared__ double rs[256], rq[256];
    rs[threadIdx.x] = s; rq[threadIdx.x] = sq;
    __syncthreads();
    for (int st = 128; st > 0; st >>= 1) {
        if (threadIdx.x < st) { rs[threadIdx.x] += rs[threadIdx.x + st]; rq[threadIdx.x] += rq[threadIdx.x + st]; }
        __syncthreads();
    }
    if (threadIdx.x == 0) { part[blk * 2] = rs[0]; part[blk * 2 + 1] = rq[0]; }
}

__global__ void stats_p2(const double* __restrict__ part, float* __restrict__ stats, int ppb) {
    int b = threadIdx.x;  // 128
    double s = 0.0, sq = 0.0;
    for (int p = 0; p < ppb; p++) { s += part[(b * ppb + p) * 2]; sq += part[(b * ppb + p) * 2 + 1]; }
    double n = 262144.0;
    double mean = s / n;
    double var = (sq - n * mean * mean) / (n - 1.0);
    stats[b * 2 + 0] = (float)(mean * 64.0);
    stats[b * 2 + 1] = (float)(sqrt(var) * 64.0);
}

// ---------------- wprep: weights -> swizzled bf16 chunks ----------------
// wcat chunk = ((side*4+d)*8 + ns)*16 + kt; elem (l*8+e) = W[n=ns*16+(l&15)][k=kt*32+(l>>4)*8+e]
//   (n<64: o_rel[k][n], else o[k][n-64])
// wpt chunk = (((side*4+d)*4 + mt)*4 + kk)*4 + nq; elem = p_w[r=mt*128+kk*32+(l>>4)*8+e][q=nq*16+(l&15)]
__global__ __launch_bounds__(256) void wprep_kernel(
    const float* __restrict__ o_xj, const float* __restrict__ o_xi,
    const float* __restrict__ p_xj, const float* __restrict__ p_xi,
    const float* __restrict__ o_rel_xj, const float* __restrict__ o_rel_xi,
    short* __restrict__ wcat, short* __restrict__ wpt) {
    int idx = blockIdx.x * 256 + threadIdx.x;   // 98304 pieces
    if (idx < 65536) {
        int l = idx & 63; int chunk = idx >> 6;
        int kt = chunk & 15, ns = (chunk >> 4) & 7, sd = chunk >> 7;
        int side = sd >> 2, dd = sd & 3;
        int n = ns * 16 + (l & 15);
        int k = kt * 32 + (l >> 4) * 8;
        const float* src = (n < 64) ? (side ? o_rel_xi : o_rel_xj)
                                    : (side ? o_xi : o_xj);
        src += (size_t)dd * 32768 + (n & 63);
        short8 v;
        #pragma unroll
        for (int e = 0; e < 8; e++) v[e] = f2bf(src[(size_t)(k + e) * 64]);
        *(short8*)(wcat + (size_t)chunk * 512 + l * 8) = v;
    } else {
        int j = idx - 65536;
        int l = j & 63; int chunk = j >> 6;
        int nq = chunk & 3, kk = (chunk >> 2) & 3, mt = (chunk >> 4) & 3, sd = chunk >> 6;
        int side = sd >> 2, dd = sd & 3;
        int q = nq * 16 + (l & 15);
        int r = mt * 128 + kk * 32 + (l >> 4) * 8;
        const float* src = (side ? p_xi : p_xj) + (size_t)dd * 32768 + q;
        short8 v;
        #pragma unroll
        for (int e = 0; e < 8; e++) v[e] = f2bf(src[(size_t)(r + e) * 64]);
        *(short8*)(wpt + (size_t)chunk * 512 + l * 8) = v;
    }
}

// ---------------- main MFMA kernel: one block per (b, side, d), XCD-swizzled ----------------
__global__ __launch_bounds__(256, 3) void main_mfma_kernel(
    const short* __restrict__ xbf, const short* __restrict__ xtbf,
    const short* __restrict__ wcat, const short* __restrict__ wpt,
    float* __restrict__ relsum, float* __restrict__ pt) {
    int blk = blockIdx.x;
    int xcd = blk & 7, rest = blk >> 3;
    int d = rest & 3, side = (rest >> 2) & 1, bhi = rest >> 3;
    int b = bhi * 8 + xcd;            // all 8 blocks of batch b share blk%8 -> same XCD
    const short* Xsw = (side ? xtbf : xbf) + (size_t)b * 262144;
    const short* Wc  = wcat + (size_t)(side * 4 + d) * 65536;
    const short* Wp  = wpt + (size_t)(side * 4 + d) * 32768;

    __shared__ __align__(16) char lds[33792];
    short* Xs  = (short*)lds;              // 8 KB (kt-loop phase)
    short* Wsh = (short*)(lds + 8192);     // 8 KB (kt-loop phase)
    short* Tos = (short*)lds;              // 17408 B overlay (pt phase): 64 x 136 shorts
    short* Wps = (short*)(lds + 17408);    // 16 KB

    int tid = threadIdx.x;
    int w = tid >> 6, l = tid & 63, li = l & 15, lg = l >> 4;
    int wm = w >> 1, wn = w & 1;

    f32x4 zero4 = {0.f, 0.f, 0.f, 0.f};
    f32x4 ptacc[4];
    #pragma unroll
    for (int i = 0; i < 4; i++) ptacc[i] = zero4;
    float esum[4] = {0.f, 0.f, 0.f, 0.f};

    for (int mt = 0; mt < 4; mt++) {
        f32x4 acc[4][4];
        #pragma unroll
        for (int i = 0; i < 4; i++)
            #pragma unroll
            for (int j = 0; j < 4; j++) acc[i][j] = zero4;

        for (int kt = 0; kt < 16; kt++) {
            __syncthreads();
            #pragma unroll
            for (int ii = 0; ii < 4; ii++) {
                int s = w * 4 + ii;
                if (s < 8)
                    gload16(Xsw + ((size_t)((mt * 8 + s) * 16 + kt)) * 512 + l * 8, Xs + s * 512);
                else
                    gload16(Wc + ((size_t)((s - 8) * 16 + kt)) * 512 + l * 8, Wsh + (s - 8) * 512);
            }
            __syncthreads();
            short8 af[4], bfv[4];
            #pragma unroll
            for (int i = 0; i < 4; i++) af[i] = *(const short8*)(Xs + (wm * 4 + i) * 512 + l * 8);
            #pragma unroll
            for (int j = 0; j < 4; j++) bfv[j] = *(const short8*)(Wsh + (wn * 4 + j) * 512 + l * 8);
            #pragma unroll
            for (int i = 0; i < 4; i++)
                #pragma unroll
                for (int j = 0; j < 4; j++)
                    acc[i][j] = __builtin_amdgcn_mfma_f32_16x16x32_bf16(af[i], bfv[j], acc[i][j], 0, 0, 0);
        }

        // prefetch Wp tile for this mt (distinct LDS region, safe to issue now)
        #pragma unroll
        for (int ii = 0; ii < 4; ii++) {
            int s = w * 4 + ii;   // s = kk*4 + nq
            gload16(Wp + ((size_t)((mt * 4 + (s >> 2)) * 4 + (s & 3))) * 512 + l * 8, Wps + s * 512);
        }
        __syncthreads();   // drains Wp loads; all waves done reading Xs/Wsh (Tos overlay safe)

        if (wn == 0) {
            // rel columns: exp colsum accumulation (col = j*16 + li)
            #pragma unroll
            for (int i = 0; i < 4; i++)
                #pragma unroll
                for (int j = 0; j < 4; j++)
                    esum[j] += __expf(acc[i][j][0]) + __expf(acc[i][j][1]) +
                               __expf(acc[i][j][2]) + __expf(acc[i][j][3]);
        } else {
            // o columns: write To^T[p][r_local] (bf16)
            #pragma unroll
            for (int i = 0; i < 4; i++)
                #pragma unroll
                for (int j = 0; j < 4; j++) {
                    int p = j * 16 + li;
                    int rb = wm * 64 + i * 16 + lg * 4;
                    short4v tv;
                    tv.x = f2bf(acc[i][j][0]); tv.y = f2bf(acc[i][j][1]);
                    tv.z = f2bf(acc[i][j][2]); tv.w = f2bf(acc[i][j][3]);
                    *(short4v*)(Tos + p * 136 + rb) = tv;
                }
        }
        __syncthreads();   // Tos visible

        // p_t += To^T @ Wp : wave w owns p rows w*16..w*16+15
        #pragma unroll
        for (int kk = 0; kk < 4; kk++) {
            short8 a = *(const short8*)(Tos + (w * 16 + li) * 136 + kk * 32 + lg * 8);
            #pragma unroll
            for (int nq = 0; nq < 4; nq++) {
                short8 bb = *(const short8*)(Wps + (kk * 4 + nq) * 512 + l * 8);
                ptacc[nq] = __builtin_amdgcn_mfma_f32_16x16x32_bf16(a, bb, ptacc[nq], 0, 0, 0);
            }
        }
    }

    __syncthreads();
    float* red = (float*)lds;
    if (wn == 0) {
        #pragma unroll
        for (int j = 0; j < 4; j++) red[wm * 256 + l * 4 + j] = esum[j];
    }
    __syncthreads();
    size_t base = (size_t)(b * 2 + side) * 4 + d;
    if (tid < 64) {
        float s = 0.f;
        #pragma unroll
        for (int w2 = 0; w2 < 2; w2++)
            #pragma unroll
            for (int g = 0; g < 4; g++)
                s += red[w2 * 256 + (g * 16 + (tid & 15)) * 4 + (tid >> 4)];
        float tot = s;
        #pragma unroll
        for (int off = 1; off < 64; off <<= 1) tot += __shfl_xor(tot, off, 64);
        relsum[base * 64 + tid] = s / tot;
    }
    float* ptout = pt + base * 4096;
    #pragma unroll
    for (int nq = 0; nq < 4; nq++)
        #pragma unroll
        for (int r = 0; r < 4; r++)
            ptout[(size_t)(w * 16 + lg * 4 + r) * 64 + nq * 16 + li] = ptacc[nq][r];
}

// ---------------- fallback fp32 fused kernel (round-1, proven) ----------------
__global__ __launch_bounds__(256) void fused_proj_kernel(
    const float* __restrict__ x,
    const float* __restrict__ o_xj, const float* __restrict__ o_xi,
    const float* __restrict__ p_xj, const float* __restrict__ p_xi,
    const float* __restrict__ o_rel_xj, const float* __restrict__ o_rel_xi,
    float* __restrict__ relsum, float* __restrict__ pt)
{
    int blk = blockIdx.x;
    int b = blk >> 3;
    int side = (blk >> 2) & 1;
    int d = blk & 3;

    const float* Wrel = (side ? o_rel_xi : o_rel_xj) + (size_t)d * (512 * 64);
    const float* Wo   = (side ? o_xi     : o_xj)     + (size_t)d * (512 * 64);
    const float* Wp   = (side ? p_xi     : p_xj)     + (size_t)d * (512 * 64);
    const float* X = x + (size_t)b * (512 * 512);

    __shared__ float Xs[16][68];
    __shared__ float Ws[16][128];
    __shared__ float To[64][68];
    __shared__ float Wps[64][68];
    __shared__ float red[16][64];
    __shared__ float cs[64];
    __shared__ float total_s;

    int tid = threadIdx.x;
    int tx = tid & 15;
    int ty = tid >> 4;

    float paccum[4][4];
    #pragma unroll
    for (int i = 0; i < 4; i++)
        #pragma unroll
        for (int j = 0; j < 4; j++) paccum[i][j] = 0.f;
    float esum[8];
    #pragma unroll
    for (int j = 0; j < 8; j++) esum[j] = 0.f;

    for (int r0 = 0; r0 < 512; r0 += 64) {
        float acc[4][8];
        #pragma unroll
        for (int i = 0; i < 4; i++)
            #pragma unroll
            for (int j = 0; j < 8; j++) acc[i][j] = 0.f;

        for (int k0 = 0; k0 < 512; k0 += 16) {
            if (side == 0) {
                int kk = tid & 15, r = tid >> 4;
                #pragma unroll
                for (int it = 0; it < 4; it++, r += 16)
                    Xs[kk][r] = X[(size_t)(r0 + r) * 512 + (k0 + kk)];
            } else {
                int r = tid & 63, kk = tid >> 6;
                #pragma unroll
                for (int it = 0; it < 4; it++, kk += 4)
                    Xs[kk][r] = X[(size_t)(k0 + kk) * 512 + (r0 + r)];
            }
            {
                int c = tid & 127, kk = tid >> 7;
                const float* Wsrc = (c < 64) ? (Wrel + c) : (Wo + (c - 64));
                #pragma unroll
                for (int it = 0; it < 8; it++, kk += 2)
                    Ws[kk][c] = Wsrc[(size_t)(k0 + kk) * 64];
            }
            __syncthreads();
            #pragma unroll
            for (int kk = 0; kk < 16; kk++) {
                float4 a  = *(const float4*)&Xs[kk][ty * 4];
                float4 b0 = *(const float4*)&Ws[kk][tx * 8];
                float4 b1 = *(const float4*)&Ws[kk][tx * 8 + 4];
                float av[4] = {a.x, a.y, a.z, a.w};
                float bv[8] = {b0.x, b0.y, b0.z, b0.w, b1.x, b1.y, b1.z, b1.w};
                #pragma unroll
                for (int i = 0; i < 4; i++)
                    #pragma unroll
                    for (int j = 0; j < 8; j++)
                        acc[i][j] = fmaf(av[i], bv[j], acc[i][j]);
            }
            __syncthreads();
        }

        if (tx < 8) {
            #pragma unroll
            for (int i = 0; i < 4; i++)
                #pragma unroll
                for (int j = 0; j < 8; j++)
                    esum[j] += expf(acc[i][j]);
        } else {
            #pragma unroll
            for (int i = 0; i < 4; i++) {
                float4 v0 = make_float4(acc[i][0], acc[i][1], acc[i][2], acc[i][3]);
                float4 v1 = make_float4(acc[i][4], acc[i][5], acc[i][6], acc[i][7]);
                *(float4*)&To[ty * 4 + i][(tx - 8) * 8]     = v0;
                *(float4*)&To[ty * 4 + i][(tx - 8) * 8 + 4] = v1;
            }
        }
        {
            int q = tid & 63, r = tid >> 6;
            #pragma unroll
            for (int it = 0; it < 16; it++, r += 4)
                Wps[r][q] = Wp[(size_t)(r0 + r) * 64 + q];
        }
        __syncthreads();
        for (int r = 0; r < 64; r++) {
            float4 aa = *(const float4*)&To[r][ty * 4];
            float4 bb = *(const float4*)&Wps[r][tx * 4];
            float av[4] = {aa.x, aa.y, aa.z, aa.w};
            float bv[4] = {bb.x, bb.y, bb.z, bb.w};
            #pragma unroll
            for (int i = 0; i < 4; i++)
                #pragma unroll
                for (int j = 0; j < 4; j++)
                    paccum[i][j] = fmaf(av[i], bv[j], paccum[i][j]);
        }
        __syncthreads();
    }

    if (tx < 8) {
        #pragma unroll
        for (int j = 0; j < 8; j++) red[ty][tx * 8 + j] = esum[j];
    }
    __syncthreads();
    if (tid < 64) {
        float s = 0.f;
        for (int t = 0; t < 16; t++) s += red[t][tid];
        cs[tid] = s;
    }
    __syncthreads();
    if (tid == 0) {
        float tot = 0.f;
        for (int i = 0; i < 64; i++) tot += cs[i];
        total_s = tot;
    }
    __syncthreads();
    size_t base = (size_t)(b * 2 + side) * 4 + d;
    if (tid < 64) relsum[base * 64 + tid] = cs[tid] / total_s;

    float* ptout = pt + base * 4096;
    #pragma unroll
    for (int i = 0; i < 4; i++)
        #pragma unroll
        for (int j = 0; j < 4; j++)
            ptout[(size_t)(ty * 4 + i) * 64 + tx * 4 + j] = paccum[i][j];
}

// ---------------- finalize per (b,d), writes contribution into ptj slot ----------------
__global__ __launch_bounds__(256) void finalize2_kernel(
    const float* __restrict__ relsum, float* __restrict__ pt,
    const float* __restrict__ p_rel_xj, const float* __restrict__ p_rel_xi,
    const float* __restrict__ stats)
{
    int blk = blockIdx.x;
    int b = blk >> 2, d = blk & 3;
    int tid = threadIdx.x, tx = tid & 15, ty = tid >> 4;
    __shared__ float Ptj[64][65], Pti[64][65], Wr[64][65];
    __shared__ float red[16][64];
    __shared__ float fj[64], fi[64];
    __shared__ float rs[256], rq[256];
    __shared__ float bc[1];

    float x_mean = stats[b * 2 + 0];
    float x_std  = stats[b * 2 + 1];

    float* ptj = pt + ((size_t)(b * 2 + 0) * 4 + d) * 4096;
    const float* pti = pt + ((size_t)(b * 2 + 1) * 4 + d) * 4096;
    for (int it = 0; it < 16; it++) {
        int idx = tid + it * 256;
        Ptj[idx >> 6][idx & 63] = ptj[idx];
        Pti[idx >> 6][idx & 63] = pti[idx];
    }
    __syncthreads();

    for (int s = 0; s < 2; s++) {
        const float* prel = (s == 0) ? (p_rel_xj + (size_t)d * 4096)
                                     : (p_rel_xi + (size_t)d * 4096);
        for (int it = 0; it < 16; it++) {
            int idx = tid + it * 256;
            Wr[idx >> 6][idx & 63] = prel[idx];
        }
        __syncthreads();
        float cpart[4] = {0.f, 0.f, 0.f, 0.f};
        for (int i = 0; i < 4; i++) {
            int p = ty * 4 + i;
            float q[4] = {0.f, 0.f, 0.f, 0.f};
            for (int r = 0; r < 64; r++) {
                float a = (s == 0) ? Ptj[p][r] : Pti[p][r];
                #pragma unroll
                for (int j = 0; j < 4; j++)
                    q[j] = fmaf(a, Wr[r][tx * 4 + j], q[j]);
            }
            #pragma unroll
            for (int j = 0; j < 4; j++) cpart[j] += __expf(q[j]);
        }
        #pragma unroll
        for (int j = 0; j < 4; j++) red[ty][tx * 4 + j] = cpart[j];
        __syncthreads();
        float* ftgt = (s == 0) ? fj : fi;
        if (tid < 64) {
            float cssum = 0.f;
            for (int t = 0; t < 16; t++) cssum += red[t][tid];
            ftgt[tid] = cssum;
        }
        __syncthreads();
        if (tid == 0) {
            float tot = 0.f;
            for (int i = 0; i < 64; i++) tot += ftgt[i];
            bc[0] = tot;
        }
        __syncthreads();
        if (tid < 64) {
            float prel_sum = ftgt[tid] / bc[0];
            float orel = relsum[((size_t)(b * 2 + s) * 4 + d) * 64 + tid];
            ftgt[tid] = sqrtf(orel / prel_sum);
        }
        __syncthreads();
    }

    float v[4][4];
    float psum = 0.f, psq = 0.f;
    #pragma unroll
    for (int i = 0; i < 4; i++) {
        int r = ty * 4 + i;
        #pragma unroll
        for (int j = 0; j < 4; j++) {
            int c = tx * 4 + j;
            float val = Ptj[r][c] * fj[r] + Pti[c][r] * fi[c];
            v[i][j] = val; psum += val; psq += val * val;
        }
    }
    rs[tid] = psum; rq[tid] = psq;
    __syncthreads();
    for (int st = 128; st > 0; st >>= 1) {
        if (tid < st) { rs[tid] += rs[tid + st]; rq[tid] += rq[tid + st]; }
        __syncthreads();
    }
    float mean = rs[0] / 4096.f;
    float var = (rq[0] - 4096.f * mean * mean) / 4095.f;
    float inv = 1.0f / (sqrtf(var) + EPSF);
    #pragma unroll
    for (int i = 0; i < 4; i++)
        #pragma unroll
        for (int j = 0; j < 4; j++)
            ptj[(size_t)(ty * 4 + i) * 64 + tx * 4 + j] = (v[i][j] - mean) * inv * x_std + x_mean;
}

// ---------------- sum over depth ----------------
__global__ __launch_bounds__(256) void sum_kernel(const float* __restrict__ pt,
                                                  float* __restrict__ out) {
    int b = blockIdx.x, tid = threadIdx.x;
    for (int it = 0; it < 16; it++) {
        int idx = tid + it * 256;
        float s = 0.f;
        #pragma unroll
        for (int d = 0; d < 4; d++)
            s += pt[((size_t)(b * 2) * 4 + d) * 4096 + idx];
        out[(size_t)b * 4096 + idx] = s;
    }
}

extern "C" void kernel_launch(void* const* d_in, const int* in_sizes, int n_in,
                              void* d_out, int out_size, void* d_ws, size_t ws_size,
                              hipStream_t stream) {
    const float* x        = (const float*)d_in[0];
    const float* o_xj     = (const float*)d_in[1];
    const float* o_xi     = (const float*)d_in[2];
    const float* p_xj     = (const float*)d_in[3];
    const float* p_xi     = (const float*)d_in[4];
    const float* o_rel_xj = (const float*)d_in[5];
    const float* o_rel_xi = (const float*)d_in[6];
    const float* p_rel_xj = (const float*)d_in[7];
    const float* p_rel_xi = (const float*)d_in[8];
    float* out = (float*)d_out;

    char* ws = (char*)d_ws;
    float*  stats  = (float*)(ws + 0);           // 1024
    float*  relsum = (float*)(ws + 1024);        // 262144
    float*  pt     = (float*)(ws + 263168);      // 16777216
    double* spartF = (double*)(ws + 17040384);   // 131072
    short*  xbf    = (short*)(ws + 17171456);    // 67108864
    short*  xtbf   = (short*)(ws + 84280320);    // 67108864
    short*  wcat   = (short*)(ws + 151389184);   // 1048576
    short*  wptb   = (short*)(ws + 152437760);   // 524288 -> end 152962048
    double* spartS = (double*)(ws + 263168);     // fallback alias inside pt region

    const size_t FAST_NEED = 152962048;
    if (ws_size >= FAST_NEED) {
        xprep_kernel<<<8192, 256, 0, stream>>>(x, xbf, xtbf, spartF);
        wprep_kernel<<<384, 256, 0, stream>>>(o_xj, o_xi, p_xj, p_xi, o_rel_xj, o_rel_xi, wcat, wptb);
        stats_p2<<<1, 128, 0, stream>>>(spartF, stats, 64);
        main_mfma_kernel<<<1024, 256, 0, stream>>>(xbf, xtbf, wcat, wptb, relsum, pt);
    } else {
        stats_p1<<<512, 256, 0, stream>>>(x, spartS);
        stats_p2<<<1, 128, 0, stream>>>(spartS, stats, 4);
        fused_proj_kernel<<<1024, 256, 0, stream>>>(x, o_xj, o_xi, p_xj, p_xi,
                                                    o_rel_xj, o_rel_xi, relsum, pt);
    }
    finalize2_kernel<<<512, 256, 0, stream>>>(relsum, pt, p_rel_xj, p_rel_xi, stats);
    sum_kernel<<<128, 256, 0, stream>>>(pt, out);
}